// Round 1
// baseline (435.335 us; speedup 1.0000x reference)
//
#include <hip/hip_runtime.h>

typedef unsigned short u16;
typedef __attribute__((ext_vector_type(8))) short frag8;
typedef __attribute__((ext_vector_type(4))) float f32x4;

static constexpr int C = 768;
static constexpr int F3 = 2304;      // 3*C
static constexpr int MROWS = 32768;  // B*T*H*W
static constexpr float LNEPS = 1e-5f;

__device__ __forceinline__ float bfu2f(u16 u){
  union { unsigned u; float f; } x; x.u = (unsigned)u << 16; return x.f;
}
__device__ __forceinline__ u16 f2bfu(float f){
  union { float f; unsigned u; } x; x.f = f;
  unsigned r = x.u + 0x7fffu + ((x.u >> 16) & 1u);   // RNE bf16
  return (u16)(r >> 16);
}

__device__ __forceinline__ void gload16(const void* g, void* l){
  __builtin_amdgcn_global_load_lds(
      (const __attribute__((address_space(1))) void*)g,
      (__attribute__((address_space(3))) void*)l, 16, 0, 0);
}

// ---------------- fp32 -> bf16 weight conversion ----------------
__global__ __launch_bounds__(256) void cvt_bf16(const float* __restrict__ src,
                                                u16* __restrict__ dst, int n){
  int i = blockIdx.x * 256 + threadIdx.x;
  if (i < n) dst[i] = f2bfu(src[i]);
}

// ---------------- LN1: fp32 x -> bf16 y ----------------
__global__ __launch_bounds__(256) void ln1_kernel(const float* __restrict__ x,
    const float* __restrict__ w, const float* __restrict__ b, u16* __restrict__ y){
  const int lane = threadIdx.x & 63, wid = threadIdx.x >> 6;
  const size_t row = (size_t)blockIdx.x * 4 + wid;
  const float4* xr = reinterpret_cast<const float4*>(x + row * C);
  float v[12];
  #pragma unroll
  for (int j = 0; j < 3; j++){
    float4 t = xr[lane + j*64];
    v[j*4+0]=t.x; v[j*4+1]=t.y; v[j*4+2]=t.z; v[j*4+3]=t.w;
  }
  float s = 0.f, ss = 0.f;
  #pragma unroll
  for (int j = 0; j < 12; j++){ s += v[j]; ss += v[j]*v[j]; }
  #pragma unroll
  for (int o = 32; o; o >>= 1){ s += __shfl_xor(s, o, 64); ss += __shfl_xor(ss, o, 64); }
  const float mu = s * (1.f/768.f);
  const float rs = rsqrtf(ss*(1.f/768.f) - mu*mu + LNEPS);
  ushort4* yr = reinterpret_cast<ushort4*>(y + row * C);
  const float4* wv = reinterpret_cast<const float4*>(w);
  const float4* bv = reinterpret_cast<const float4*>(b);
  #pragma unroll
  for (int j = 0; j < 3; j++){
    float4 wj = wv[lane + j*64], bj = bv[lane + j*64];
    ushort4 o4;
    o4.x = f2bfu((v[j*4+0]-mu)*rs*wj.x + bj.x);
    o4.y = f2bfu((v[j*4+1]-mu)*rs*wj.y + bj.y);
    o4.z = f2bfu((v[j*4+2]-mu)*rs*wj.z + bj.z);
    o4.w = f2bfu((v[j*4+3]-mu)*rs*wj.w + bj.w);
    yr[lane + j*64] = o4;
  }
}

// ---------------- GEMM: C[m,n] = sum_k A[m,k]*B[n,k]  (B^T layout) ----------------
// MODE 0: out = bf16(acc + bias)            (qkv projection)
// MODE 1: out = fp32(acc + bias + resid)    (out projection + residual)
template<int MODE>
__global__ __launch_bounds__(256) void gemm_bt(
    const u16* __restrict__ A, const u16* __restrict__ Bw,
    const float* __restrict__ bias, const float* __restrict__ resid,
    void* __restrict__ Cout, int Ndim, int K)
{
  __shared__ __align__(16) u16 lA[128*32];
  __shared__ __align__(16) u16 lB[128*32];
  const int tid = threadIdx.x;
  const int lane = tid & 63, wid = tid >> 6;
  const int ntn = Ndim >> 7;
  const int bm = blockIdx.x / ntn, bn = blockIdx.x % ntn;
  const int m0 = bm << 7, n0 = bn << 7;
  const int wr = wid >> 1, wc = wid & 1;

  // staging: per thread one 16B chunk per issue; 2 issues per operand
  const int srow = tid >> 2, scol = (tid & 3) * 8;
  const u16* gA = A + (size_t)(m0 + srow) * K + scol;
  const u16* gB = Bw + (size_t)(n0 + srow) * K + scol;
  char* lAb = (char*)lA + wid * 1024;
  char* lBb = (char*)lB + wid * 1024;

  f32x4 acc[4][4] = {};

  const int fr = lane & 15, fk = (lane >> 4) * 8;
  const u16* pa = &lA[(wr*64 + fr)*32 + fk];
  const u16* pb = &lB[(wc*64 + fr)*32 + fk];

  for (int kt = 0; kt < K; kt += 32){
    gload16(gA + kt,                 lAb);
    gload16(gA + kt + 64*(size_t)K,  lAb + 4096);
    gload16(gB + kt,                 lBb);
    gload16(gB + kt + 64*(size_t)K,  lBb + 4096);
    __syncthreads();   // compiler drains vmcnt before barrier
    frag8 af[4], bfr[4];
    #pragma unroll
    for (int i = 0; i < 4; i++){
      af[i]  = *reinterpret_cast<const frag8*>(pa + i*16*32);
      bfr[i] = *reinterpret_cast<const frag8*>(pb + i*16*32);
    }
    #pragma unroll
    for (int i = 0; i < 4; i++)
      #pragma unroll
      for (int j = 0; j < 4; j++)
        acc[i][j] = __builtin_amdgcn_mfma_f32_16x16x32_bf16(af[i], bfr[j], acc[i][j], 0, 0, 0);
    __syncthreads();
  }

  // epilogue: C/D frag layout col=lane&15, row=(lane>>4)*4+r  [m89-verified]
  const int er = (lane >> 4) * 4, ec = lane & 15;
  #pragma unroll
  for (int j = 0; j < 4; j++){
    const int col = n0 + wc*64 + j*16 + ec;
    const float bv = bias[col];
    #pragma unroll
    for (int i = 0; i < 4; i++){
      #pragma unroll
      for (int r = 0; r < 4; r++){
        const size_t row = (size_t)(m0 + wr*64 + i*16 + er + r);
        float v = acc[i][j][r] + bv;
        if (MODE == 0) ((u16*)Cout)[row * Ndim + col] = f2bfu(v);
        else           ((float*)Cout)[row * Ndim + col] = v + resid[row * Ndim + col];
      }
    }
  }
}

// ---------------- attention over T=16, one wave per (b,h,w,head) ----------------
// qkv row layout per head n: f = n*192 + [0:64)=q [64:128)=k [128:192)=v
// output o (16x64) overwrites the v-slots (already staged to LDS before write).
__global__ __launch_bounds__(64) void attn_kernel(u16* __restrict__ qkv){
  __shared__ __align__(16) u16 sq[16][72];
  __shared__ __align__(16) u16 sk[16][72];
  __shared__ __align__(16) u16 sv[16][72];
  __shared__ float sp[16][17];
  const int lane = threadIdx.x;
  int bid = blockIdx.x;
  const int n = bid % 12; bid /= 12;
  const int w = bid % 32; bid /= 32;
  const int h = bid % 32; const int b = bid / 32;
  u16* base = qkv + ((size_t)(b*16384 + h*32 + w)) * F3 + n * 192;
  const size_t tstride = (size_t)1024 * F3;   // t-step = 1024 rows

  // stage q,k,v: 16 rows x 24 chunks of 8 bf16 = 384 chunks, 6 per lane
  #pragma unroll
  for (int i = 0; i < 6; i++){
    const int e8 = lane + i*64;
    const int t = e8 / 24, ck = e8 % 24;
    uint4 val = *reinterpret_cast<const uint4*>(base + (size_t)t*tstride + ck*8);
    u16* dst = (ck < 8) ? &sq[t][ck*8] : (ck < 16) ? &sk[t][(ck-8)*8] : &sv[t][(ck-16)*8];
    *reinterpret_cast<uint4*>(dst) = val;
  }
  __syncthreads();

  // scores: lane owns rows t = (lane>>4)+4i, col s = lane&15
  const int g = lane >> 4, sj = lane & 15;
  float accv[4] = {0.f, 0.f, 0.f, 0.f};
  #pragma unroll
  for (int dc = 0; dc < 8; dc++){
    union { uint4 u; u16 s[8]; } kc;
    kc.u = *reinterpret_cast<const uint4*>(&sk[sj][dc*8]);
    #pragma unroll
    for (int i = 0; i < 4; i++){
      union { uint4 u; u16 s[8]; } qc;
      qc.u = *reinterpret_cast<const uint4*>(&sq[g + i*4][dc*8]);
      #pragma unroll
      for (int e = 0; e < 8; e++)
        accv[i] += bfu2f(qc.s[e]) * bfu2f(kc.s[e]);
    }
  }
  // softmax over s (16-lane groups)
  #pragma unroll
  for (int i = 0; i < 4; i++){
    float sc = accv[i] * 0.125f;
    float mx = sc;
    #pragma unroll
    for (int o = 1; o < 16; o <<= 1) mx = fmaxf(mx, __shfl_xor(mx, o, 16));
    float p = __expf(sc - mx);
    float sm = p;
    #pragma unroll
    for (int o = 1; o < 16; o <<= 1) sm += __shfl_xor(sm, o, 16);
    sp[g + i*4][sj] = p / sm;
  }
  __syncthreads();

  // PV: lane owns d-column = lane
  #pragma unroll
  for (int t = 0; t < 16; t++){
    float o = 0.f;
    #pragma unroll
    for (int s = 0; s < 16; s++) o += sp[t][s] * bfu2f(sv[s][lane]);
    base[(size_t)t*tstride + 128 + lane] = f2bfu(o);
  }
}

// ---------------- LN2: reads attention output from v-slots of qkv ----------------
__global__ __launch_bounds__(256) void ln2_kernel(const u16* __restrict__ qkv,
    const float* __restrict__ w, const float* __restrict__ b, u16* __restrict__ y2){
  const int lane = threadIdx.x & 63, wid = threadIdx.x >> 6;
  const size_t row = (size_t)blockIdx.x * 4 + wid;
  const u16* src = qkv + row * F3 + 128;
  float v[12];
  #pragma unroll
  for (int j = 0; j < 12; j++) v[j] = bfu2f(src[j*192 + lane]);   // c = j*64+lane
  float s = 0.f, ss = 0.f;
  #pragma unroll
  for (int j = 0; j < 12; j++){ s += v[j]; ss += v[j]*v[j]; }
  #pragma unroll
  for (int o = 32; o; o >>= 1){ s += __shfl_xor(s, o, 64); ss += __shfl_xor(ss, o, 64); }
  const float mu = s * (1.f/768.f);
  const float rs = rsqrtf(ss*(1.f/768.f) - mu*mu + LNEPS);
  #pragma unroll
  for (int j = 0; j < 12; j++){
    const int c = j*64 + lane;
    y2[row * C + c] = f2bfu((v[j]-mu)*rs*w[c] + b[c]);
  }
}

extern "C" void kernel_launch(void* const* d_in, const int* in_sizes, int n_in,
                              void* d_out, int out_size, void* d_ws, size_t ws_size,
                              hipStream_t stream){
  const float* x    = (const float*)d_in[0];
  const float* ln1w = (const float*)d_in[1];
  const float* ln1b = (const float*)d_in[2];
  const float* Wqkv = (const float*)d_in[3];
  const float* bqkv = (const float*)d_in[4];
  const float* ln2w = (const float*)d_in[5];
  const float* ln2b = (const float*)d_in[6];
  const float* Wout = (const float*)d_in[7];
  const float* bout = (const float*)d_in[8];
  float* out = (float*)d_out;

  char* ws = (char*)d_ws;
  u16* qkv = (u16*)ws;                       // 32768*2304*2 = 150,994,944 B
  u16* y   = (u16*)(ws + 150994944);         // 32768*768*2  =  50,331,648 B (y1, then y2)
  u16* wq  = (u16*)(ws + 201326592);         // 2304*768*2   =   3,538,944 B
  u16* wo  = (u16*)(ws + 204865536);         // 768*768*2    =   1,179,648 B  (total 206,045,184)

  cvt_bf16<<<(F3*C + 255)/256, 256, 0, stream>>>(Wqkv, wq, F3*C);
  cvt_bf16<<<(C*C + 255)/256, 256, 0, stream>>>(Wout, wo, C*C);
  ln1_kernel<<<MROWS/4, 256, 0, stream>>>(x, ln1w, ln1b, y);
  gemm_bt<0><<<(MROWS/128)*(F3/128), 256, 0, stream>>>(y, wq, bqkv, nullptr, qkv, F3, C);
  attn_kernel<<<2*32*32*12, 64, 0, stream>>>(qkv);
  ln2_kernel<<<MROWS/4, 256, 0, stream>>>(qkv, ln2w, ln2b, y);
  gemm_bt<1><<<(MROWS/128)*(C/128), 256, 0, stream>>>(y, wo, bout, x, out, C, C);
}